// Round 1
// baseline (50.383 us; speedup 1.0000x reference)
//
#include <hip/hip_runtime.h>

// RoI crop-and-resize pooling.
// feature_map: (8, 64, 64, 256) f32 NHWC
// roi_bboxes:  (8, 300, 4) f32  (y_lo, x_lo, y_hi, x_hi), coords in [0,1]
// out:         (8, 300, 7, 7, 256) f32
//
// One float4 output element per thread; c4 innermost -> coalesced gathers/stores.

constexpr int B  = 8;
constexpr int N  = 300;
constexpr int H  = 64;
constexpr int W  = 64;
constexpr int C  = 256;
constexpr int C4 = C / 4;          // 64 float4 per pixel
constexpr int PH = 7;
constexpr int PW = 7;
constexpr int TOTAL4 = B * N * PH * PW * C4;  // 7,526,400

__global__ __launch_bounds__(256) void roipool_kernel(
    const float* __restrict__ fm,
    const float* __restrict__ boxes,
    float* __restrict__ out)
{
    int idx = blockIdx.x * blockDim.x + threadIdx.x;
    if (idx >= TOTAL4) return;

    int c4   = idx & (C4 - 1);
    int rest = idx >> 6;            // box*49 + ph*7 + pw
    int pw   = rest % PW;
    int t2   = rest / PW;
    int ph   = t2 % PH;
    int box  = t2 / PH;             // b*N + n
    int bimg = box / N;

    const float4 bx = reinterpret_cast<const float4*>(boxes)[box];
    // bx = (y_lo, x_lo, y_hi, x_hi)

    float ty = (float)ph / 6.0f;
    float tx = (float)pw / 6.0f;
    float y  = (bx.x + ty * (bx.z - bx.x)) * (float)(H - 1);
    float x  = (bx.y + tx * (bx.w - bx.y)) * (float)(W - 1);

    bool valid = (y >= 0.0f) && (y <= (float)(H - 1)) &&
                 (x >= 0.0f) && (x <= (float)(W - 1));

    float y0f = floorf(y), x0f = floorf(x);
    float wy = y - y0f;
    float wx = x - x0f;

    int y0 = (int)fminf(fmaxf(y0f,        0.0f), (float)(H - 1));
    int y1 = (int)fminf(fmaxf(y0f + 1.0f, 0.0f), (float)(H - 1));
    int x0 = (int)fminf(fmaxf(x0f,        0.0f), (float)(W - 1));
    int x1 = (int)fminf(fmaxf(x0f + 1.0f, 0.0f), (float)(W - 1));

    const float4* f = reinterpret_cast<const float4*>(fm);
    int rowb = (bimg * H + y0) * W;   // top row, in pixels
    int rowt = (bimg * H + y1) * W;   // bottom row

    float4 tl = f[(rowb + x0) * C4 + c4];
    float4 tr = f[(rowb + x1) * C4 + c4];
    float4 bl = f[(rowt + x0) * C4 + c4];
    float4 br = f[(rowt + x1) * C4 + c4];

    float4 v;
    {
        float top, bot;
        top = tl.x + (tr.x - tl.x) * wx;
        bot = bl.x + (br.x - bl.x) * wx;
        v.x = top + (bot - top) * wy;
        top = tl.y + (tr.y - tl.y) * wx;
        bot = bl.y + (br.y - bl.y) * wx;
        v.y = top + (bot - top) * wy;
        top = tl.z + (tr.z - tl.z) * wx;
        bot = bl.z + (br.z - bl.z) * wx;
        v.z = top + (bot - top) * wy;
        top = tl.w + (tr.w - tl.w) * wx;
        bot = bl.w + (br.w - bl.w) * wx;
        v.w = top + (bot - top) * wy;
    }

    if (!valid) { v.x = 0.0f; v.y = 0.0f; v.z = 0.0f; v.w = 0.0f; }

    reinterpret_cast<float4*>(out)[idx] = v;
}

extern "C" void kernel_launch(void* const* d_in, const int* in_sizes, int n_in,
                              void* d_out, int out_size, void* d_ws, size_t ws_size,
                              hipStream_t stream) {
    const float* fm    = (const float*)d_in[0];
    const float* boxes = (const float*)d_in[1];
    float* out         = (float*)d_out;

    int blocks = (TOTAL4 + 255) / 256;
    roipool_kernel<<<blocks, 256, 0, stream>>>(fm, boxes, out);
}

// Round 3
// 33.583 us; speedup vs baseline: 1.5003x; 1.5003x over previous
//
#include <hip/hip_runtime.h>

// RoI crop-and-resize pooling.
// feature_map: (8, 64, 64, 256) f32 NHWC
// roi_bboxes:  (8, 300, 4) f32  (y_lo, x_lo, y_hi, x_hi), coords in [0,1]
// out:         (8, 300, 7, 7, 256) f32
//
// One float4 output element per thread; c4 innermost -> coalesced gathers/stores.
// R2/R3: chunked XCD swizzle (1 image per XCD -> fm slice fits 4MB L2) +
//        nontemporal output stores (write stream stops evicting fm from L2).
//        Use clang ext_vector_type for the nontemporal builtin (HIP float4 is
//        a class and is rejected by __builtin_nontemporal_store).

typedef float f32x4 __attribute__((ext_vector_type(4)));

constexpr int B  = 8;
constexpr int N  = 300;
constexpr int H  = 64;
constexpr int W  = 64;
constexpr int C  = 256;
constexpr int C4 = C / 4;          // 64 float4 per pixel
constexpr int PH = 7;
constexpr int PW = 7;
constexpr int TOTAL4 = B * N * PH * PW * C4;  // 7,526,400
constexpr int NBLK   = TOTAL4 / 256;          // 29,400 (divisible)
constexpr int NXCD   = 8;
constexpr int CPX    = NBLK / NXCD;           // 3,675 = exactly one image's blocks

__global__ __launch_bounds__(256) void roipool_kernel(
    const float* __restrict__ fm,
    const float* __restrict__ boxes,
    float* __restrict__ out)
{
    // Bijective chunked XCD swizzle: hardware assigns blockIdx round-robin to
    // XCDs (xcd = bid % 8); relabel so each XCD gets a contiguous 1/8 chunk of
    // the work = exactly one image's 300 boxes. NBLK % NXCD == 0 -> bijective.
    int bid = blockIdx.x;
    int swz = (bid & (NXCD - 1)) * CPX + (bid >> 3);
    int idx = swz * 256 + (int)threadIdx.x;

    int c4   = idx & (C4 - 1);
    int rest = idx >> 6;            // box*49 + ph*7 + pw
    int pw   = rest % PW;
    int t2   = rest / PW;
    int ph   = t2 % PH;
    int box  = t2 / PH;             // b*N + n
    int bimg = box / N;

    const f32x4 bx = reinterpret_cast<const f32x4*>(boxes)[box];
    // bx = (y_lo, x_lo, y_hi, x_hi)

    float ty = (float)ph / 6.0f;
    float tx = (float)pw / 6.0f;
    float y  = (bx.x + ty * (bx.z - bx.x)) * (float)(H - 1);
    float x  = (bx.y + tx * (bx.w - bx.y)) * (float)(W - 1);

    bool valid = (y >= 0.0f) && (y <= (float)(H - 1)) &&
                 (x >= 0.0f) && (x <= (float)(W - 1));

    float y0f = floorf(y), x0f = floorf(x);
    float wy = y - y0f;
    float wx = x - x0f;

    int y0 = (int)fminf(fmaxf(y0f,        0.0f), (float)(H - 1));
    int y1 = (int)fminf(fmaxf(y0f + 1.0f, 0.0f), (float)(H - 1));
    int x0 = (int)fminf(fmaxf(x0f,        0.0f), (float)(W - 1));
    int x1 = (int)fminf(fmaxf(x0f + 1.0f, 0.0f), (float)(W - 1));

    const f32x4* f = reinterpret_cast<const f32x4*>(fm);
    int rowb = (bimg * H + y0) * W;   // top row, in pixels
    int rowt = (bimg * H + y1) * W;   // bottom row

    f32x4 tl = f[(rowb + x0) * C4 + c4];
    f32x4 tr = f[(rowb + x1) * C4 + c4];
    f32x4 bl = f[(rowt + x0) * C4 + c4];
    f32x4 br = f[(rowt + x1) * C4 + c4];

    f32x4 top = tl + (tr - tl) * wx;
    f32x4 bot = bl + (br - bl) * wx;
    f32x4 v   = top + (bot - top) * wy;

    if (!valid) v = (f32x4)0.0f;

    __builtin_nontemporal_store(v, reinterpret_cast<f32x4*>(out) + idx);
}

extern "C" void kernel_launch(void* const* d_in, const int* in_sizes, int n_in,
                              void* d_out, int out_size, void* d_ws, size_t ws_size,
                              hipStream_t stream) {
    const float* fm    = (const float*)d_in[0];
    const float* boxes = (const float*)d_in[1];
    float* out         = (float*)d_out;

    roipool_kernel<<<NBLK, 256, 0, stream>>>(fm, boxes, out);
}

// Round 4
// 30.660 us; speedup vs baseline: 1.6433x; 1.0953x over previous
//
#include <hip/hip_runtime.h>

// RoI crop-and-resize pooling.
// feature_map: (8, 64, 64, 256) f32 NHWC
// roi_bboxes:  (8, 300, 4) f32  (y_lo, x_lo, y_hi, x_hi), coords in [0,1]
// out:         (8, 300, 7, 7, 256) f32
//
// R3: XCD swizzle + NT stores -> 33.6us.
// R4: 2 outputs per thread (same pixel, c4 and c4+32): coord math amortized
//     2x, 8 gathers in flight per thread (2x MLP). Grid 14700 blocks; general
//     bijective XCD swizzle (14700 % 8 != 0).

typedef float f32x4 __attribute__((ext_vector_type(4)));

constexpr int B  = 8;
constexpr int N  = 300;
constexpr int H  = 64;
constexpr int W  = 64;
constexpr int C  = 256;
constexpr int C4 = C / 4;          // 64 float4 per pixel
constexpr int PH = 7;
constexpr int PW = 7;
constexpr int TOTAL4 = B * N * PH * PW * C4;  // 7,526,400 float4 outputs
constexpr int NBLK   = TOTAL4 / 512;          // 14,700 blocks (256 thr, 2 out/thr)
constexpr int NXCD   = 8;
constexpr int SWZ_Q  = NBLK / NXCD;           // 1837
constexpr int SWZ_R  = NBLK % NXCD;           // 4

__global__ __launch_bounds__(256) void roipool_kernel(
    const float* __restrict__ fm,
    const float* __restrict__ boxes,
    float* __restrict__ out)
{
    // Bijective chunked XCD swizzle (general q/r form since NBLK % 8 != 0):
    // xcd = bid % 8 gets a contiguous chunk of q (+1 for first r) block ids.
    int bid  = blockIdx.x;
    int xcd  = bid & (NXCD - 1);
    int base = (xcd < SWZ_R) ? xcd * (SWZ_Q + 1) : SWZ_R * (SWZ_Q + 1) + (xcd - SWZ_R) * SWZ_Q;
    int swz  = base + (bid >> 3);

    int tid = (int)threadIdx.x;
    int p   = tid >> 5;             // pixel within block, 0..7
    int c   = tid & 31;             // c4 lane within pixel half, 0..31

    int pix  = swz * 8 + p;         // global pixel index: box*49 + ph*7 + pw
    int pw   = pix % PW;
    int t2   = pix / PW;
    int ph   = t2 % PH;
    int box  = t2 / PH;             // b*N + n
    int bimg = box / N;

    const f32x4 bx = reinterpret_cast<const f32x4*>(boxes)[box];
    // bx = (y_lo, x_lo, y_hi, x_hi)

    float ty = (float)ph / 6.0f;
    float tx = (float)pw / 6.0f;
    float y  = (bx.x + ty * (bx.z - bx.x)) * (float)(H - 1);
    float x  = (bx.y + tx * (bx.w - bx.y)) * (float)(W - 1);

    bool valid = (y >= 0.0f) && (y <= (float)(H - 1)) &&
                 (x >= 0.0f) && (x <= (float)(W - 1));

    float y0f = floorf(y), x0f = floorf(x);
    float wy = y - y0f;
    float wx = x - x0f;

    int y0 = (int)fminf(fmaxf(y0f,        0.0f), (float)(H - 1));
    int y1 = (int)fminf(fmaxf(y0f + 1.0f, 0.0f), (float)(H - 1));
    int x0 = (int)fminf(fmaxf(x0f,        0.0f), (float)(W - 1));
    int x1 = (int)fminf(fmaxf(x0f + 1.0f, 0.0f), (float)(W - 1));

    const f32x4* f = reinterpret_cast<const f32x4*>(fm);
    int btl = ((bimg * H + y0) * W + x0) * C4;
    int btr = ((bimg * H + y0) * W + x1) * C4;
    int bbl = ((bimg * H + y1) * W + x0) * C4;
    int bbr = ((bimg * H + y1) * W + x1) * C4;

    // 8 independent gathers (2 c4 positions x 4 corners)
    f32x4 tl0 = f[btl + c];
    f32x4 tr0 = f[btr + c];
    f32x4 bl0 = f[bbl + c];
    f32x4 br0 = f[bbr + c];
    f32x4 tl1 = f[btl + c + 32];
    f32x4 tr1 = f[btr + c + 32];
    f32x4 bl1 = f[bbl + c + 32];
    f32x4 br1 = f[bbr + c + 32];

    f32x4 top0 = tl0 + (tr0 - tl0) * wx;
    f32x4 bot0 = bl0 + (br0 - bl0) * wx;
    f32x4 v0   = top0 + (bot0 - top0) * wy;
    f32x4 top1 = tl1 + (tr1 - tl1) * wx;
    f32x4 bot1 = bl1 + (br1 - bl1) * wx;
    f32x4 v1   = top1 + (bot1 - top1) * wy;

    if (!valid) { v0 = (f32x4)0.0f; v1 = (f32x4)0.0f; }

    f32x4* o = reinterpret_cast<f32x4*>(out) + pix * C4 + c;
    __builtin_nontemporal_store(v0, o);
    __builtin_nontemporal_store(v1, o + 32);
}

extern "C" void kernel_launch(void* const* d_in, const int* in_sizes, int n_in,
                              void* d_out, int out_size, void* d_ws, size_t ws_size,
                              hipStream_t stream) {
    const float* fm    = (const float*)d_in[0];
    const float* boxes = (const float*)d_in[1];
    float* out         = (float*)d_out;

    roipool_kernel<<<NBLK, 256, 0, stream>>>(fm, boxes, out);
}

// Round 5
// 30.149 us; speedup vs baseline: 1.6711x; 1.0169x over previous
//
#include <hip/hip_runtime.h>

// RoI crop-and-resize pooling.
// feature_map: (8, 64, 64, 256) f32 NHWC
// roi_bboxes:  (8, 300, 4) f32  (y_lo, x_lo, y_hi, x_hi), coords in [0,1]
// out:         (8, 300, 7, 7, 256) f32
//
// R3: XCD swizzle + NT stores -> 33.6us.  R4: 2 out/thread -> 30.7us.
// R5: 4 outputs per thread (same pixel, c4 lanes c, c+16, c+32, c+48):
//     coord math amortized 4x, 16 gathers in flight per thread.

typedef float f32x4 __attribute__((ext_vector_type(4)));

constexpr int B  = 8;
constexpr int N  = 300;
constexpr int H  = 64;
constexpr int W  = 64;
constexpr int C  = 256;
constexpr int C4 = C / 4;          // 64 float4 per pixel
constexpr int PH = 7;
constexpr int PW = 7;
constexpr int TOTAL4 = B * N * PH * PW * C4;  // 7,526,400 float4 outputs
constexpr int NBLK   = TOTAL4 / 1024;         // 7,350 blocks (256 thr, 4 out/thr)
constexpr int NXCD   = 8;
constexpr int SWZ_Q  = NBLK / NXCD;           // 918
constexpr int SWZ_R  = NBLK % NXCD;           // 6

__global__ __launch_bounds__(256) void roipool_kernel(
    const float* __restrict__ fm,
    const float* __restrict__ boxes,
    float* __restrict__ out)
{
    // Bijective chunked XCD swizzle (general q/r form since NBLK % 8 != 0).
    int bid  = blockIdx.x;
    int xcd  = bid & (NXCD - 1);
    int base = (xcd < SWZ_R) ? xcd * (SWZ_Q + 1) : SWZ_R * (SWZ_Q + 1) + (xcd - SWZ_R) * SWZ_Q;
    int swz  = base + (bid >> 3);

    int tid = (int)threadIdx.x;
    int p   = tid >> 4;             // pixel within block, 0..15
    int c   = tid & 15;             // c4 lane within pixel quarter, 0..15

    int pix  = swz * 16 + p;        // global pixel index: box*49 + ph*7 + pw
    int pw   = pix % PW;
    int t2   = pix / PW;
    int ph   = t2 % PH;
    int box  = t2 / PH;             // b*N + n
    int bimg = box / N;

    const f32x4 bx = reinterpret_cast<const f32x4*>(boxes)[box];
    // bx = (y_lo, x_lo, y_hi, x_hi)

    float ty = (float)ph / 6.0f;
    float tx = (float)pw / 6.0f;
    float y  = (bx.x + ty * (bx.z - bx.x)) * (float)(H - 1);
    float x  = (bx.y + tx * (bx.w - bx.y)) * (float)(W - 1);

    bool valid = (y >= 0.0f) && (y <= (float)(H - 1)) &&
                 (x >= 0.0f) && (x <= (float)(W - 1));

    float y0f = floorf(y), x0f = floorf(x);
    float wy = y - y0f;
    float wx = x - x0f;

    int y0 = (int)fminf(fmaxf(y0f,        0.0f), (float)(H - 1));
    int y1 = (int)fminf(fmaxf(y0f + 1.0f, 0.0f), (float)(H - 1));
    int x0 = (int)fminf(fmaxf(x0f,        0.0f), (float)(W - 1));
    int x1 = (int)fminf(fmaxf(x0f + 1.0f, 0.0f), (float)(W - 1));

    const f32x4* f = reinterpret_cast<const f32x4*>(fm);
    int btl = ((bimg * H + y0) * W + x0) * C4 + c;
    int btr = ((bimg * H + y0) * W + x1) * C4 + c;
    int bbl = ((bimg * H + y1) * W + x0) * C4 + c;
    int bbr = ((bimg * H + y1) * W + x1) * C4 + c;

    // 16 independent gathers (4 c4 positions x 4 corners)
    f32x4 tl0 = f[btl];      f32x4 tr0 = f[btr];
    f32x4 bl0 = f[bbl];      f32x4 br0 = f[bbr];
    f32x4 tl1 = f[btl + 16]; f32x4 tr1 = f[btr + 16];
    f32x4 bl1 = f[bbl + 16]; f32x4 br1 = f[bbr + 16];
    f32x4 tl2 = f[btl + 32]; f32x4 tr2 = f[btr + 32];
    f32x4 bl2 = f[bbl + 32]; f32x4 br2 = f[bbr + 32];
    f32x4 tl3 = f[btl + 48]; f32x4 tr3 = f[btr + 48];
    f32x4 bl3 = f[bbl + 48]; f32x4 br3 = f[bbr + 48];

    f32x4 top, bot, v0, v1, v2, v3;
    top = tl0 + (tr0 - tl0) * wx;  bot = bl0 + (br0 - bl0) * wx;
    v0  = top + (bot - top) * wy;
    top = tl1 + (tr1 - tl1) * wx;  bot = bl1 + (br1 - bl1) * wx;
    v1  = top + (bot - top) * wy;
    top = tl2 + (tr2 - tl2) * wx;  bot = bl2 + (br2 - bl2) * wx;
    v2  = top + (bot - top) * wy;
    top = tl3 + (tr3 - tl3) * wx;  bot = bl3 + (br3 - bl3) * wx;
    v3  = top + (bot - top) * wy;

    if (!valid) {
        v0 = (f32x4)0.0f; v1 = (f32x4)0.0f;
        v2 = (f32x4)0.0f; v3 = (f32x4)0.0f;
    }

    f32x4* o = reinterpret_cast<f32x4*>(out) + pix * C4 + c;
    __builtin_nontemporal_store(v0, o);
    __builtin_nontemporal_store(v1, o + 16);
    __builtin_nontemporal_store(v2, o + 32);
    __builtin_nontemporal_store(v3, o + 48);
}

extern "C" void kernel_launch(void* const* d_in, const int* in_sizes, int n_in,
                              void* d_out, int out_size, void* d_ws, size_t ws_size,
                              hipStream_t stream) {
    const float* fm    = (const float*)d_in[0];
    const float* boxes = (const float*)d_in[1];
    float* out         = (float*)d_out;

    roipool_kernel<<<NBLK, 256, 0, stream>>>(fm, boxes, out);
}